// Round 1
// baseline (514.330 us; speedup 1.0000x reference)
//
#include <hip/hip_runtime.h>
#include <hip/hip_bf16.h>

#define D_INP 4096
#define D_OUT 4096

using f32x4  = __attribute__((ext_vector_type(4))) float;
using bf16x8 = __attribute__((ext_vector_type(8))) short;

static __device__ __forceinline__ unsigned short f2bf(float f) {
    union { __hip_bfloat16 h; unsigned short u; } cv;
    cv.h = __float2bfloat16(f);
    return cv.u;
}

// ---- prep: x (fp32) -> bf16 bits --------------------------------------------
__global__ __launch_bounds__(256) void prep_x_kernel(const float4* __restrict__ in,
                                                     ushort4* __restrict__ out, int n4) {
    for (int i = blockIdx.x * blockDim.x + threadIdx.x; i < n4; i += gridDim.x * blockDim.x) {
        float4 a = in[i];
        ushort4 o;
        o.x = f2bf(a.x); o.y = f2bf(a.y); o.z = f2bf(a.z); o.w = f2bf(a.w);
        out[i] = o;
    }
}

// ---- prep: W = sw*sm + bb (fp32) -> bf16 bits -------------------------------
__global__ __launch_bounds__(256) void prep_w_kernel(const float4* __restrict__ sw,
                                                     const float4* __restrict__ sm,
                                                     const float4* __restrict__ bb,
                                                     ushort4* __restrict__ out, int n4) {
    for (int i = blockIdx.x * blockDim.x + threadIdx.x; i < n4; i += gridDim.x * blockDim.x) {
        float4 a = sw[i], m = sm[i], b = bb[i];
        ushort4 o;
        o.x = f2bf(a.x * m.x + b.x);
        o.y = f2bf(a.y * m.y + b.y);
        o.z = f2bf(a.z * m.z + b.z);
        o.w = f2bf(a.w * m.w + b.w);
        out[i] = o;
    }
}

// ---- main GEMM: C[M,N] = A[M,K] * B[N,K]^T + bias ---------------------------
// m97 structure: 128x128 tile, BK=64, 4 waves (2x2) of 64x64 each,
// mfma_f32_16x16x32_bf16, global_load_lds width-16 staging, linear LDS.
__global__ __launch_bounds__(256) void gemm_bf16(const short* __restrict__ A,  // [M][K] bf16
                                                 const short* __restrict__ B,  // [N][K] bf16
                                                 const float* __restrict__ bias,
                                                 float* __restrict__ C,
                                                 int M, int N, int K) {
    constexpr int BM = 128, BN = 128, BK = 64;
    __shared__ short As[BM * BK];
    __shared__ short Bs[BN * BK];

    const int tid  = threadIdx.x;
    const int lane = tid & 63;
    const int wid  = tid >> 6;            // 0..3
    const int wm   = (wid >> 1) * 64;     // wave row offset inside tile
    const int wn   = (wid & 1) * 64;      // wave col offset inside tile
    const int bm   = blockIdx.x * BM;
    const int bn   = blockIdx.y * BN;

    const int l15 = lane & 15;
    const int l4  = lane >> 4;

    f32x4 acc[4][4] = {};   // 4x4 fragments of 16x16 per wave = 64x64

    for (int kt = 0; kt < K; kt += BK) {
        // ---- stage A,B tile -> LDS (4 chunks of 16B per thread per tile) ----
        // chunk c = it*256 + wid*64 + lane; row = c>>3, k-chunk = c&7.
        // LDS dest is wave-uniform base + lane*16 (hardware semantics).
#pragma unroll
        for (int it = 0; it < 4; ++it) {
            const int c   = it * 256 + wid * 64 + lane;
            const int row = c >> 3;
            const int kc  = (c & 7) * 8;
            const int ldsbase = (it * 256 + wid * 64) * 8;  // element idx, wave-uniform
            __builtin_amdgcn_global_load_lds(
                (const __attribute__((address_space(1))) void*)(A + (size_t)(bm + row) * K + kt + kc),
                (__attribute__((address_space(3))) void*)(As + ldsbase), 16, 0, 0);
            __builtin_amdgcn_global_load_lds(
                (const __attribute__((address_space(1))) void*)(B + (size_t)(bn + row) * K + kt + kc),
                (__attribute__((address_space(3))) void*)(Bs + ldsbase), 16, 0, 0);
        }
        __syncthreads();

        // ---- compute: 2 k-steps of K=32, 16 MFMA each -----------------------
#pragma unroll
        for (int ks = 0; ks < 2; ++ks) {
            bf16x8 af[4], bfr[4];
            const int ko = ks * 32 + l4 * 8;
#pragma unroll
            for (int i = 0; i < 4; ++i) {
                af[i]  = *reinterpret_cast<const bf16x8*>(&As[(wm + i * 16 + l15) * BK + ko]);
                bfr[i] = *reinterpret_cast<const bf16x8*>(&Bs[(wn + i * 16 + l15) * BK + ko]);
            }
#pragma unroll
            for (int i = 0; i < 4; ++i)
#pragma unroll
                for (int j = 0; j < 4; ++j)
                    acc[i][j] = __builtin_amdgcn_mfma_f32_16x16x32_bf16(af[i], bfr[j], acc[i][j], 0, 0, 0);
        }
        __syncthreads();
    }

    // ---- epilogue: C/D layout col=lane&15, row=(lane>>4)*4+reg (m89/m91) ----
#pragma unroll
    for (int j = 0; j < 4; ++j) {
        const int col = bn + wn + j * 16 + l15;
        const float bv = bias[col];
#pragma unroll
        for (int i = 0; i < 4; ++i) {
            const int rowbase = bm + wm + i * 16 + l4 * 4;
#pragma unroll
            for (int r = 0; r < 4; ++r) {
                C[(size_t)(rowbase + r) * N + col] = acc[i][j][r] + bv;
            }
        }
    }
}

// ---- fp32 fallback (only if workspace too small; slow but correct) ----------
__global__ __launch_bounds__(256) void fallback_gemm(const float* __restrict__ X,
                                                     const float* __restrict__ SW,
                                                     const float* __restrict__ SM,
                                                     const float* __restrict__ BB,
                                                     const float* __restrict__ bias,
                                                     float* __restrict__ C,
                                                     int M, int N, int K) {
    __shared__ float Xs[32][33];
    __shared__ float Ws[32][33];
    const int tid = threadIdx.x;
    const int tx = tid & 31;   // col in tile
    const int ty = tid >> 5;   // 0..7
    const int bm = blockIdx.x * 32, bn = blockIdx.y * 32;
    float acc[4] = {0.f, 0.f, 0.f, 0.f};
    for (int kt = 0; kt < K; kt += 32) {
#pragma unroll
        for (int r = 0; r < 4; ++r) {
            const int row = ty + r * 8;
            Xs[row][tx] = X[(size_t)(bm + row) * K + kt + tx];
            const size_t wi = (size_t)(bn + row) * K + kt + tx;
            Ws[row][tx] = SW[wi] * SM[wi] + BB[wi];
        }
        __syncthreads();
#pragma unroll 8
        for (int k = 0; k < 32; ++k) {
            const float wv = Ws[tx][k];
#pragma unroll
            for (int r = 0; r < 4; ++r)
                acc[r] += Xs[ty + r * 8][k] * wv;
        }
        __syncthreads();
    }
#pragma unroll
    for (int r = 0; r < 4; ++r)
        C[(size_t)(bm + ty + r * 8) * N + bn + tx] = acc[r] + bias[bn + tx];
}

extern "C" void kernel_launch(void* const* d_in, const int* in_sizes, int n_in,
                              void* d_out, int out_size, void* d_ws, size_t ws_size,
                              hipStream_t stream) {
    const float* x    = (const float*)d_in[0];
    const float* sw   = (const float*)d_in[1];
    const float* sm   = (const float*)d_in[2];
    const float* bb   = (const float*)d_in[3];
    const float* bias = (const float*)d_in[4];
    float* out = (float*)d_out;

    const int K = D_INP;
    const int N = D_OUT;
    const int M = in_sizes[0] / K;   // 4*2048 = 8192

    const size_t xb_bytes = (size_t)M * K * sizeof(short);   // 67,108,864
    const size_t wb_bytes = (size_t)N * K * sizeof(short);   // 33,554,432

    if (ws_size < xb_bytes + wb_bytes) {
        dim3 grid(M / 32, N / 32);
        fallback_gemm<<<grid, 256, 0, stream>>>(x, sw, sm, bb, bias, out, M, N, K);
        return;
    }

    short* xb = (short*)d_ws;
    short* wb = (short*)((char*)d_ws + xb_bytes);

    prep_x_kernel<<<2048, 256, 0, stream>>>((const float4*)x, (ushort4*)xb, (M * K) / 4);
    prep_w_kernel<<<2048, 256, 0, stream>>>((const float4*)sw, (const float4*)sm,
                                            (const float4*)bb, (ushort4*)wb, (N * K) / 4);

    dim3 grid(M / 128, N / 128);
    gemm_bf16<<<grid, 256, 0, stream>>>(xb, wb, bias, out, M, N, K);
}

// Round 2
// 384.443 us; speedup vs baseline: 1.3379x; 1.3379x over previous
//
#include <hip/hip_runtime.h>
#include <hip/hip_bf16.h>

#define D_INP 4096
#define D_OUT 4096
#define KK    4096
#define NN    4096

using f32x4  = __attribute__((ext_vector_type(4))) float;
using bf16x8 = __attribute__((ext_vector_type(8))) short;

static __device__ __forceinline__ unsigned short f2bf(float f) {
    union { __hip_bfloat16 h; unsigned short u; } cv;
    cv.h = __float2bfloat16(f);
    return cv.u;
}

// ---- prep: x (fp32) -> bf16 bits --------------------------------------------
__global__ __launch_bounds__(256) void prep_x_kernel(const float4* __restrict__ in,
                                                     ushort4* __restrict__ out, int n4) {
    for (int i = blockIdx.x * blockDim.x + threadIdx.x; i < n4; i += gridDim.x * blockDim.x) {
        float4 a = in[i];
        ushort4 o;
        o.x = f2bf(a.x); o.y = f2bf(a.y); o.z = f2bf(a.z); o.w = f2bf(a.w);
        out[i] = o;
    }
}

// ---- prep: W = sw + bb (sw is pre-masked: sw*sm == sw exactly) --------------
__global__ __launch_bounds__(256) void prep_w_kernel(const float4* __restrict__ sw,
                                                     const float4* __restrict__ bb,
                                                     ushort4* __restrict__ out, int n4) {
    for (int i = blockIdx.x * blockDim.x + threadIdx.x; i < n4; i += gridDim.x * blockDim.x) {
        float4 a = sw[i], b = bb[i];
        ushort4 o;
        o.x = f2bf(a.x + b.x);
        o.y = f2bf(a.y + b.y);
        o.z = f2bf(a.z + b.z);
        o.w = f2bf(a.w + b.w);
        out[i] = o;
    }
}

// ---- main GEMM: C[M,N] = A[M,K] * B[N,K]^T + bias ---------------------------
// 256x256 tile, BK=32, 8 waves (2M x 4N), 4-deep LDS ring, distance-3 prefetch,
// counted vmcnt(8), per-phase {ds_read || stage || barrier || MFMA} interleave,
// swizzled LDS (slot ^= (row>>1)&3) via pre-swizzled global source (rule #21).
__global__ __launch_bounds__(512, 2) void gemm_8p(const short* __restrict__ A,  // [M][K] bf16
                                                  const short* __restrict__ B,  // [N][K] bf16
                                                  const float* __restrict__ bias,
                                                  float* __restrict__ C, int M) {
    constexpr int BK = 32;
    constexpr int NT = KK / BK;        // 128 K-tiles
    __shared__ short As[4][256 * BK];  // 4 x 16KB
    __shared__ short Bs[4][256 * BK];  // 4 x 16KB  (total 128 KiB)

    const int tid  = threadIdx.x;
    const int lane = tid & 63;
    const int w    = tid >> 6;         // 0..7
    const int wr   = w >> 2;           // 0..1 -> 128-row band
    const int wc   = w & 3;            // 0..3 -> 64-col band
    const int l15  = lane & 15;
    const int l4   = lane >> 4;

    // XCD-bijective swizzle (nwg = 512, divisible by 8)
    const int bid = blockIdx.x;
    const int swz = (bid & 7) * 64 + (bid >> 3);
    const int tm  = swz >> 4;          // 0..31  (M/256 = 32)
    const int tn  = swz & 15;          // 0..15  (N/256 = 16)
    const int bm  = tm * 256, bn = tn * 256;

    // ds_read fragment addressing (swizzled): idx = row*32 + (c0 ^ ((row>>1)&3))*8
    const int slx    = (l15 >> 1) & 3;
    const int a_base = (wr * 128 + l15) * BK + ((l4 ^ slx) * 8);   // + m*512
    const int b_base = (wc * 64  + l15) * BK + ((l4 ^ slx) * 8);   // + n*512

    // staging lane constants: chunk = 16 rows x 64B; lane -> (row, slot)
    const int st_row = lane >> 2;                      // 0..15
    const int st_c0  = (lane & 3) ^ ((lane >> 3) & 3); // inverse-swizzled col group
    const size_t a_src0 = (size_t)(bm + st_row) * KK + st_c0 * 8;
    const size_t b_src0 = (size_t)(bn + st_row) * KK + st_c0 * 8;

    f32x4 acc[8][4] = {};

#define STAGE_A(t, c)                                                                 \
    __builtin_amdgcn_global_load_lds(                                                 \
        (const __attribute__((address_space(1))) void*)(A + a_src0 + (size_t)(c) * 16 * KK + (t) * BK), \
        (__attribute__((address_space(3))) void*)(&As[(t) & 3][(c) * 512]), 16, 0, 0)
#define STAGE_B(t, c)                                                                 \
    __builtin_amdgcn_global_load_lds(                                                 \
        (const __attribute__((address_space(1))) void*)(B + b_src0 + (size_t)(c) * 16 * KK + (t) * BK), \
        (__attribute__((address_space(3))) void*)(&Bs[(t) & 3][(c) * 512]), 16, 0, 0)

    // prologue: stage tiles 0,1,2 (12 loads/wave), wait tile 0 (8 outstanding ok)
    for (int t = 0; t < 3; ++t) {
        STAGE_A(t, w);     STAGE_B(t, w);
        STAGE_A(t, w + 8); STAGE_B(t, w + 8);
    }
    asm volatile("s_waitcnt vmcnt(8)" ::: "memory");
    __builtin_amdgcn_s_barrier();
    asm volatile("" ::: "memory");

    for (int t = 0; t < NT; ++t) {
        const short* Ab = As[t & 3];
        const short* Bb = Bs[t & 3];
        bf16x8 bfr[4], af[4];

        // ---------------- phase 0 : quadrant m=0..3 ----------------
#pragma unroll
        for (int n = 0; n < 4; ++n) bfr[n] = *(const bf16x8*)&Bb[b_base + n * 512];
#pragma unroll
        for (int m = 0; m < 4; ++m) af[m] = *(const bf16x8*)&Ab[a_base + m * 512];
        if (t + 3 < NT) { STAGE_A(t + 3, w); STAGE_B(t + 3, w); }
        __builtin_amdgcn_s_barrier();
        asm volatile("s_waitcnt lgkmcnt(0)" ::: "memory");
        __builtin_amdgcn_s_setprio(1);
#pragma unroll
        for (int m = 0; m < 4; ++m)
#pragma unroll
            for (int n = 0; n < 4; ++n)
                acc[m][n] = __builtin_amdgcn_mfma_f32_16x16x32_bf16(af[m], bfr[n], acc[m][n], 0, 0, 0);
        __builtin_amdgcn_s_setprio(0);
        __builtin_amdgcn_s_barrier();
        asm volatile("" ::: "memory");

        // ---------------- phase 1 : quadrant m=4..7 ----------------
#pragma unroll
        for (int m = 0; m < 4; ++m) af[m] = *(const bf16x8*)&Ab[a_base + (m + 4) * 512];
        if (t + 3 < NT) { STAGE_A(t + 3, w + 8); STAGE_B(t + 3, w + 8); }
        // counted vmcnt: tile t+1 must have landed; tiles t+2,t+3 stay in flight
        if (t + 3 < NT)      { asm volatile("s_waitcnt vmcnt(8)" ::: "memory"); }
        else if (t + 2 < NT) { asm volatile("s_waitcnt vmcnt(4)" ::: "memory"); }
        else                 { asm volatile("s_waitcnt vmcnt(0)" ::: "memory"); }
        __builtin_amdgcn_s_barrier();
        asm volatile("s_waitcnt lgkmcnt(0)" ::: "memory");
        __builtin_amdgcn_s_setprio(1);
#pragma unroll
        for (int m = 0; m < 4; ++m)
#pragma unroll
            for (int n = 0; n < 4; ++n)
                acc[m + 4][n] = __builtin_amdgcn_mfma_f32_16x16x32_bf16(af[m], bfr[n], acc[m + 4][n], 0, 0, 0);
        __builtin_amdgcn_s_setprio(0);
        __builtin_amdgcn_s_barrier();
        asm volatile("" ::: "memory");
    }
#undef STAGE_A
#undef STAGE_B

    // epilogue: C/D layout col=lane&15, row=(lane>>4)*4+reg (verified R1)
#pragma unroll
    for (int n = 0; n < 4; ++n) {
        const int col = bn + wc * 64 + n * 16 + l15;
        const float bv = bias[col];
#pragma unroll
        for (int m = 0; m < 8; ++m) {
            const int row0 = bm + wr * 128 + m * 16 + l4 * 4;
#pragma unroll
            for (int r = 0; r < 4; ++r)
                C[(size_t)(row0 + r) * NN + col] = acc[m][n][r] + bv;
        }
    }
}

// ---- fp32 fallback (only if workspace too small / odd shape) ----------------
__global__ __launch_bounds__(256) void fallback_gemm(const float* __restrict__ X,
                                                     const float* __restrict__ SW,
                                                     const float* __restrict__ SM,
                                                     const float* __restrict__ BB,
                                                     const float* __restrict__ bias,
                                                     float* __restrict__ C,
                                                     int M, int N, int K) {
    __shared__ float Xs[32][33];
    __shared__ float Ws[32][33];
    const int tid = threadIdx.x;
    const int tx = tid & 31;
    const int ty = tid >> 5;
    const int bm = blockIdx.x * 32, bn = blockIdx.y * 32;
    float acc[4] = {0.f, 0.f, 0.f, 0.f};
    for (int kt = 0; kt < K; kt += 32) {
#pragma unroll
        for (int r = 0; r < 4; ++r) {
            const int row = ty + r * 8;
            Xs[row][tx] = X[(size_t)(bm + row) * K + kt + tx];
            const size_t wi = (size_t)(bn + row) * K + kt + tx;
            Ws[row][tx] = SW[wi] * SM[wi] + BB[wi];
        }
        __syncthreads();
#pragma unroll 8
        for (int k = 0; k < 32; ++k) {
            const float wv = Ws[tx][k];
#pragma unroll
            for (int r = 0; r < 4; ++r)
                acc[r] += Xs[ty + r * 8][k] * wv;
        }
        __syncthreads();
    }
#pragma unroll
    for (int r = 0; r < 4; ++r)
        C[(size_t)(bm + ty + r * 8) * N + bn + tx] = acc[r] + bias[bn + tx];
}

extern "C" void kernel_launch(void* const* d_in, const int* in_sizes, int n_in,
                              void* d_out, int out_size, void* d_ws, size_t ws_size,
                              hipStream_t stream) {
    const float* x    = (const float*)d_in[0];
    const float* sw   = (const float*)d_in[1];
    const float* sm   = (const float*)d_in[2];
    const float* bb   = (const float*)d_in[3];
    const float* bias = (const float*)d_in[4];
    float* out = (float*)d_out;

    const int K = D_INP;
    const int N = D_OUT;
    const int M = in_sizes[0] / K;   // 8192

    const size_t xb_bytes = (size_t)M * K * sizeof(short);
    const size_t wb_bytes = (size_t)N * K * sizeof(short);

    if (ws_size < xb_bytes + wb_bytes || (M % 256) != 0 || N != NN || K != KK) {
        dim3 grid(M / 32, N / 32);
        fallback_gemm<<<grid, 256, 0, stream>>>(x, sw, sm, bb, bias, out, M, N, K);
        return;
    }

    short* xb = (short*)d_ws;
    short* wb = (short*)((char*)d_ws + xb_bytes);

    prep_x_kernel<<<2048, 256, 0, stream>>>((const float4*)x, (ushort4*)xb, (M * K) / 4);
    prep_w_kernel<<<2048, 256, 0, stream>>>((const float4*)sw, (const float4*)bb,
                                            (ushort4*)wb, (N * K) / 4);

    const int nwg = (M / 256) * (N / 256);   // 512
    gemm_8p<<<nwg, 512, 0, stream>>>(xb, wb, bias, out, M);
}

// Round 4
// 374.873 us; speedup vs baseline: 1.3720x; 1.0255x over previous
//
#include <hip/hip_runtime.h>
#include <hip/hip_bf16.h>

#define KK 4096
#define NN 4096

using f32x4  = __attribute__((ext_vector_type(4))) float;
using bf16x8 = __attribute__((ext_vector_type(8))) short;

static __device__ __forceinline__ unsigned short f2bf(float f) {
    union { __hip_bfloat16 h; unsigned short u; } cv;
    cv.h = __float2bfloat16(f);
    return cv.u;
}

// ---- prep: x (fp32) -> bf16 bits --------------------------------------------
__global__ __launch_bounds__(256) void prep_x_kernel(const float4* __restrict__ in,
                                                     ushort4* __restrict__ out, int n4) {
    for (int i = blockIdx.x * blockDim.x + threadIdx.x; i < n4; i += gridDim.x * blockDim.x) {
        float4 a = in[i];
        ushort4 o;
        o.x = f2bf(a.x); o.y = f2bf(a.y); o.z = f2bf(a.z); o.w = f2bf(a.w);
        out[i] = o;
    }
}

// ---- prep: W = sw + bb (sw is pre-masked: sw*sm == sw exactly) --------------
__global__ __launch_bounds__(256) void prep_w_kernel(const float4* __restrict__ sw,
                                                     const float4* __restrict__ bb,
                                                     ushort4* __restrict__ out, int n4) {
    for (int i = blockIdx.x * blockDim.x + threadIdx.x; i < n4; i += gridDim.x * blockDim.x) {
        float4 a = sw[i], b = bb[i];
        ushort4 o;
        o.x = f2bf(a.x + b.x);
        o.y = f2bf(a.y + b.y);
        o.z = f2bf(a.z + b.z);
        o.w = f2bf(a.w + b.w);
        out[i] = o;
    }
}

// ---- main GEMM: C[M,N] = A[M,K] * B[N,K]^T + bias ---------------------------
// m201 8-phase template: 256x256 tile, BK=64, 8 waves (2Mx4N), dbuf=2 x 2 halves,
// slot^=(row&7) LDS swizzle via pre-swizzled global source, counted vmcnt(4)
// at phases 4/8 only, setprio(1) around each 16-MFMA quadrant.
__global__ __launch_bounds__(512, 2) void gemm_8p(const short* __restrict__ A,  // [M][K] bf16
                                                  const short* __restrict__ B,  // [N][K] bf16
                                                  const float* __restrict__ bias,
                                                  float* __restrict__ C, int M) {
    __shared__ __align__(16) short As[2][2][8192];  // [buf][half][128 rows x 64 k]
    __shared__ __align__(16) short Bs[2][2][8192];

    const int tid  = threadIdx.x;
    const int lane = tid & 63;
    const int w    = tid >> 6;         // 0..7
    const int wr   = w >> 2;           // 0..1 (A half = wr)
    const int wc   = w & 3;            // 0..3
    const int bh   = wc >> 1;          // B half
    const int l15  = lane & 15;
    const int l4   = lane >> 4;        // 0..3
    const int l7   = lane & 7;

    // XCD-bijective swizzle (nwg = 512, divisible by 8)
    const int bid = blockIdx.x;
    const int swz = (bid & 7) * 64 + (bid >> 3);
    const int bm  = (swz >> 4) * 256;   // 32 M-tiles
    const int bn  = (swz & 15) * 256;   // 16 N-tiles

    // stage addressing: per wave-instr 8 rows x 128B; lane -> (row=l>>3, slot=l&7)
    // LDS[r][s] must hold G[r][s ^ (r&7)]  ->  global col-slot = (l&7) ^ (l>>3)
    const int srow = lane >> 3;
    const int scol = (l7 ^ srow) * 8;   // shorts
    const short* Abase = A + (size_t)bm * KK + scol;
    const short* Bbase = B + (size_t)bn * KK + scol;

#define STAGE_A(t, h)                                                                      \
    do {                                                                                   \
        _Pragma("unroll") for (int j = 0; j < 2; ++j) {                                    \
            const int rr = (h) * 128 + (w * 2 + j) * 8 + srow;                             \
            __builtin_amdgcn_global_load_lds(                                              \
                (const __attribute__((address_space(1))) void*)(Abase + (size_t)rr * KK + (t) * 64), \
                (__attribute__((address_space(3))) void*)(&As[(t) & 1][h][(w * 2 + j) * 512]), \
                16, 0, 0);                                                                 \
        }                                                                                  \
    } while (0)
#define STAGE_B(t, h)                                                                      \
    do {                                                                                   \
        _Pragma("unroll") for (int j = 0; j < 2; ++j) {                                    \
            const int rr = (h) * 128 + (w * 2 + j) * 8 + srow;                             \
            __builtin_amdgcn_global_load_lds(                                              \
                (const __attribute__((address_space(1))) void*)(Bbase + (size_t)rr * KK + (t) * 64), \
                (__attribute__((address_space(3))) void*)(&Bs[(t) & 1][h][(w * 2 + j) * 512]), \
                16, 0, 0);                                                                 \
        }                                                                                  \
    } while (0)

    // fragment LDS indices (shorts), swizzled: slot = ((ks<<2)|l4) ^ (row&7), row&7 == l7
#define AIDX(m, ks) ((((m) * 16 + l15) * 64) + (((((ks) << 2) | l4) ^ l7) * 8))
#define BIDX(n, ks) (((((wc & 1) * 64 + (n) * 16 + l15) * 64) + (((((ks) << 2) | l4) ^ l7) * 8)))

#define PH_PRE()                                              \
    __builtin_amdgcn_s_barrier();                             \
    asm volatile("s_waitcnt lgkmcnt(0)" ::: "memory");        \
    __builtin_amdgcn_s_setprio(1)
#define PH_POST()                                             \
    __builtin_amdgcn_s_setprio(0);                            \
    __builtin_amdgcn_s_barrier();                             \
    asm volatile("" ::: "memory")

#define MM(ACCM, ACCN, AF, BF)                                                             \
    _Pragma("unroll") for (int m = 0; m < 4; ++m)                                          \
        _Pragma("unroll") for (int n = 0; n < 2; ++n)                                      \
            _Pragma("unroll") for (int ks = 0; ks < 2; ++ks)                               \
                acc[(ACCM) + m][(ACCN) + n] = __builtin_amdgcn_mfma_f32_16x16x32_bf16(     \
                    AF[m][ks], BF[n][ks], acc[(ACCM) + m][(ACCN) + n], 0, 0, 0)

    f32x4 acc[8][4] = {};

    // prologue: tile0 (all 4 halves) -> buf0 ; tile1 B halves -> buf1
    STAGE_A(0, 0); STAGE_A(0, 1);
    STAGE_B(0, 0); STAGE_B(0, 1);
    STAGE_B(1, 0); STAGE_B(1, 1);
    asm volatile("s_waitcnt vmcnt(4)" ::: "memory");   // tile0's 8 loads landed
    __builtin_amdgcn_s_barrier();
    asm volatile("" ::: "memory");

    const int NITER = KK / 128;   // 32 iterations, 2 K-tiles each
    for (int i = 0; i < NITER; ++i) {
        const int t = 2 * i;
        const bool more = (i < NITER - 1);
        bf16x8 af[4][2], af2[4][2], bf[2][2], bf2[2][2];

        // ---- P1: read A m0-3 + B n0-1 (tile t, buf0); stage A(t+1) h0 ----
#pragma unroll
        for (int m = 0; m < 4; ++m)
#pragma unroll
            for (int ks = 0; ks < 2; ++ks) af[m][ks] = *(const bf16x8*)&As[0][wr][AIDX(m, ks)];
#pragma unroll
        for (int n = 0; n < 2; ++n)
#pragma unroll
            for (int ks = 0; ks < 2; ++ks) bf[n][ks] = *(const bf16x8*)&Bs[0][bh][BIDX(n, ks)];
        STAGE_A(t + 1, 0);
        PH_PRE();
        MM(0, 0, af, bf);
        PH_POST();

        // ---- P2: read B n2-3; stage A(t+1) h1 ----
#pragma unroll
        for (int n = 0; n < 2; ++n)
#pragma unroll
            for (int ks = 0; ks < 2; ++ks) bf2[n][ks] = *(const bf16x8*)&Bs[0][bh][BIDX(n + 2, ks)];
        STAGE_A(t + 1, 1);
        PH_PRE();
        MM(0, 2, af, bf2);
        PH_POST();

        // ---- P3: read A m4-7; stage B(t+2) h0 ----
#pragma unroll
        for (int m = 0; m < 4; ++m)
#pragma unroll
            for (int ks = 0; ks < 2; ++ks) af2[m][ks] = *(const bf16x8*)&As[0][wr][AIDX(m + 4, ks)];
        if (more) STAGE_B(t + 2, 0);
        PH_PRE();
        MM(4, 0, af2, bf);
        PH_POST();

        // ---- P4: stage B(t+2) h1; counted vmcnt ----
        if (more) STAGE_B(t + 2, 1);
        PH_PRE();
        MM(4, 2, af2, bf2);
        __builtin_amdgcn_s_setprio(0);
        if (more) { asm volatile("s_waitcnt vmcnt(4)" ::: "memory"); }
        else      { asm volatile("s_waitcnt vmcnt(0)" ::: "memory"); }
        __builtin_amdgcn_s_barrier();
        asm volatile("" ::: "memory");

        // ---- P5: read tile t+1 (buf1) A m0-3 + B n0-1; stage A(t+2) h0 ----
#pragma unroll
        for (int m = 0; m < 4; ++m)
#pragma unroll
            for (int ks = 0; ks < 2; ++ks) af[m][ks] = *(const bf16x8*)&As[1][wr][AIDX(m, ks)];
#pragma unroll
        for (int n = 0; n < 2; ++n)
#pragma unroll
            for (int ks = 0; ks < 2; ++ks) bf[n][ks] = *(const bf16x8*)&Bs[1][bh][BIDX(n, ks)];
        if (more) STAGE_A(t + 2, 0);
        PH_PRE();
        MM(0, 0, af, bf);
        PH_POST();

        // ---- P6: read B n2-3; stage A(t+2) h1 ----
#pragma unroll
        for (int n = 0; n < 2; ++n)
#pragma unroll
            for (int ks = 0; ks < 2; ++ks) bf2[n][ks] = *(const bf16x8*)&Bs[1][bh][BIDX(n + 2, ks)];
        if (more) STAGE_A(t + 2, 1);
        PH_PRE();
        MM(0, 2, af, bf2);
        PH_POST();

        // ---- P7: read A m4-7; stage B(t+3) h0 ----
#pragma unroll
        for (int m = 0; m < 4; ++m)
#pragma unroll
            for (int ks = 0; ks < 2; ++ks) af2[m][ks] = *(const bf16x8*)&As[1][wr][AIDX(m + 4, ks)];
        if (more) STAGE_B(t + 3, 0);
        PH_PRE();
        MM(4, 0, af2, bf);
        PH_POST();

        // ---- P8: stage B(t+3) h1; counted vmcnt ----
        if (more) STAGE_B(t + 3, 1);
        PH_PRE();
        MM(4, 2, af2, bf2);
        __builtin_amdgcn_s_setprio(0);
        if (more) { asm volatile("s_waitcnt vmcnt(4)" ::: "memory"); }
        else      { asm volatile("s_waitcnt vmcnt(0)" ::: "memory"); }
        __builtin_amdgcn_s_barrier();
        asm volatile("" ::: "memory");
    }

#undef STAGE_A
#undef STAGE_B
#undef AIDX
#undef BIDX
#undef PH_PRE
#undef PH_POST
#undef MM

    // epilogue: C/D layout col=lane&15, row=(lane>>4)*4+reg (verified R1/R2)
#pragma unroll
    for (int n = 0; n < 4; ++n) {
        const int col = bn + wc * 64 + n * 16 + l15;
        const float bv = bias[col];
#pragma unroll
        for (int m = 0; m < 8; ++m) {
            const int row0 = bm + wr * 128 + m * 16 + l4 * 4;
#pragma unroll
            for (int r = 0; r < 4; ++r)
                C[(size_t)(row0 + r) * NN + col] = acc[m][n][r] + bv;
        }
    }
}

// ---- fp32 fallback (only if workspace too small / odd shape) ----------------
__global__ __launch_bounds__(256) void fallback_gemm(const float* __restrict__ X,
                                                     const float* __restrict__ SW,
                                                     const float* __restrict__ SM,
                                                     const float* __restrict__ BB,
                                                     const float* __restrict__ bias,
                                                     float* __restrict__ C,
                                                     int M, int N, int K) {
    __shared__ float Xs[32][33];
    __shared__ float Ws[32][33];
    const int tid = threadIdx.x;
    const int tx = tid & 31;
    const int ty = tid >> 5;
    const int bm = blockIdx.x * 32, bn = blockIdx.y * 32;
    float acc[4] = {0.f, 0.f, 0.f, 0.f};
    for (int kt = 0; kt < K; kt += 32) {
#pragma unroll
        for (int r = 0; r < 4; ++r) {
            const int row = ty + r * 8;
            Xs[row][tx] = X[(size_t)(bm + row) * K + kt + tx];
            const size_t wi = (size_t)(bn + row) * K + kt + tx;
            Ws[row][tx] = SW[wi] * SM[wi] + BB[wi];
        }
        __syncthreads();
#pragma unroll 8
        for (int k = 0; k < 32; ++k) {
            const float wv = Ws[tx][k];
#pragma unroll
            for (int r = 0; r < 4; ++r)
                acc[r] += Xs[ty + r * 8][k] * wv;
        }
        __syncthreads();
    }
#pragma unroll
    for (int r = 0; r < 4; ++r)
        C[(size_t)(bm + ty + r * 8) * N + bn + tx] = acc[r] + bias[bn + tx];
}

extern "C" void kernel_launch(void* const* d_in, const int* in_sizes, int n_in,
                              void* d_out, int out_size, void* d_ws, size_t ws_size,
                              hipStream_t stream) {
    const float* x    = (const float*)d_in[0];
    const float* sw   = (const float*)d_in[1];
    const float* sm   = (const float*)d_in[2];
    const float* bb   = (const float*)d_in[3];
    const float* bias = (const float*)d_in[4];
    float* out = (float*)d_out;

    const int K = 4096;
    const int N = 4096;
    const int M = in_sizes[0] / K;   // 8192

    const size_t xb_bytes = (size_t)M * K * sizeof(short);
    const size_t wb_bytes = (size_t)N * K * sizeof(short);

    if (ws_size < xb_bytes + wb_bytes || (M % 256) != 0 || in_sizes[1] != N * K) {
        dim3 grid(M / 32, N / 32);
        fallback_gemm<<<grid, 256, 0, stream>>>(x, sw, sm, bb, bias, out, M, N, K);
        return;
    }

    short* xb = (short*)d_ws;
    short* wb = (short*)((char*)d_ws + xb_bytes);

    prep_x_kernel<<<2048, 256, 0, stream>>>((const float4*)x, (ushort4*)xb, (M * K) / 4);
    prep_w_kernel<<<2048, 256, 0, stream>>>((const float4*)sw, (const float4*)bb,
                                            (ushort4*)wb, (N * K) / 4);

    const int nwg = (M / 256) * (N / 256);   // 512
    gemm_8p<<<nwg, 512, 0, stream>>>(xb, wb, bias, out, M);
}